// Round 4
// baseline (496.663 us; speedup 1.0000x reference)
//
#include <hip/hip_runtime.h>
#include <hip/hip_bf16.h>
#include <stdint.h>

#define NNODES 50000
#define NEDGES 800000
#define CH     256
#define NCLS   64

typedef __attribute__((ext_vector_type(8))) short  short8;
typedef __attribute__((ext_vector_type(4))) float  floatx4;

__device__ __forceinline__ float bf2f(unsigned short u) {
    union { unsigned int i; float f; } v; v.i = ((unsigned int)u) << 16; return v.f;
}
__device__ __forceinline__ unsigned short f2bf(float f) {
    union { float f; unsigned int i; } v; v.f = f;
    unsigned int x = v.i;
    return (unsigned short)((x + 0x7fffu + ((x >> 16) & 1u)) >> 16);  // RNE
}

// ---------------- fused setup: zero deg + transpose-convert all 3 weights ----------------
__global__ void k_setup(const float* __restrict__ W0, const float* __restrict__ W1,
                        const float* __restrict__ Wl,
                        unsigned short* __restrict__ w0t, unsigned short* __restrict__ w1t,
                        unsigned short* __restrict__ wlt, int* __restrict__ deg) {
    int i = blockIdx.x * 256 + threadIdx.x;
    if (i < 65536) {
        int r = i >> 8, c = i & 255;
        w0t[c * 256 + r] = f2bf(W0[i]);
    } else if (i < 131072) {
        int j = i - 65536;
        int r = j >> 8, c = j & 255;
        w1t[c * 256 + r] = f2bf(W1[j]);
    } else if (i < 147456) {
        int j = i - 131072;
        int r = j >> 6, c = j & 63;       // Wl is [256,64]
        wlt[c * 256 + r] = f2bf(Wl[j]);
    } else if (i < 147456 + NNODES) {
        deg[i - 147456] = 0;
    }
}

__global__ void k_hist(const int* __restrict__ dst, int* __restrict__ deg) {
    int e = blockIdx.x * 256 + threadIdx.x;
    if (e < NEDGES) {
        int d = dst[e];
        if ((unsigned)d < NNODES) atomicAdd(&deg[d], 1);
    }
}

__global__ void k_scan1(const int* __restrict__ in, int* __restrict__ out,
                        int* __restrict__ part, int n) {
    __shared__ int sm[256];
    int i = blockIdx.x * 256 + threadIdx.x;
    int v = (i < n) ? in[i] : 0;
    sm[threadIdx.x] = v;
    __syncthreads();
    for (int off = 1; off < 256; off <<= 1) {
        int t = (threadIdx.x >= (unsigned)off) ? sm[threadIdx.x - off] : 0;
        __syncthreads();
        sm[threadIdx.x] += t;
        __syncthreads();
    }
    if (i < n) out[i] = sm[threadIdx.x];
    if (threadIdx.x == 255) part[blockIdx.x] = sm[255];
}

__global__ void k_scan3(const int* __restrict__ scn, const int* __restrict__ deg,
                        const int* __restrict__ part, int* __restrict__ offs,
                        int* __restrict__ cursor, int n) {
    int i = blockIdx.x * 256 + threadIdx.x;
    if (i < n) {
        int add = (blockIdx.x > 0) ? part[blockIdx.x - 1] : 0;
        int o = scn[i] - deg[i] + add;
        offs[i] = o; cursor[i] = o;
    }
}

__global__ void k_scatter(const int* __restrict__ dst, const int* __restrict__ src,
                          int* __restrict__ cursor, int* __restrict__ esrc) {
    int e = blockIdx.x * 256 + threadIdx.x;
    if (e < NEDGES) {
        int d = dst[e];
        if ((unsigned)d < NNODES) {
            int p = atomicAdd(&cursor[d], 1);
            if ((unsigned)p < NEDGES) esrc[p] = src[e];
        }
    }
}

// ---------------- GEMM, LDS-free: C[M,N], 64 rows/block (16/wave), B read as fragments ----
// B (pre-transposed, [N][256]) is L2-resident (<=128 KB). Lane l of wave w:
//   A fragment: row m0+w*16+(l&15), k = k0 + (l>>4)*8   (16B contiguous)
//   B fragment: row nt*16+(l&15),   k = k0 + (l>>4)*8   (direct MFMA layout)
// No staging, no barriers, no LDS. HEL>0 fuses el/er epilogue (needs BN==N==CH).
template<int BN, bool ABF16, bool OUTF32, int HEL>
__global__ __launch_bounds__(256) void k_gemmd(const void* __restrict__ Av,
                                               const unsigned short* __restrict__ BT,
                                               const float* __restrict__ bias,
                                               float* __restrict__ Cf,
                                               unsigned short* __restrict__ Cb,
                                               int M, int N,
                                               const float* __restrict__ al,
                                               const float* __restrict__ ar,
                                               float* __restrict__ el,
                                               float* __restrict__ er) {
    constexpr int NT = BN / 16;
    const int t  = threadIdx.x;
    const int w  = t >> 6, l = t & 63;
    const int lm = l & 15, lk = (l >> 4) * 8;
    const int m0 = blockIdx.x * 64;
    const int arow = m0 + w * 16 + lm;            // A-fragment row of this lane
    const float* Af = (const float*)Av;
    const unsigned short* Ab = (const unsigned short*)Av;
    const unsigned short* Bl = BT + (size_t)lm * 256 + lk;   // lane-local B base

    floatx4 acc[NT];
#pragma unroll
    for (int nt = 0; nt < NT; ++nt) acc[nt] = (floatx4)0.0f;

#pragma unroll 2
    for (int ks = 0; ks < 8; ++ks) {
        const int k0 = ks * 32;
        short8 af = (short8)0;
        if (ABF16) {
            if (arow < M) af = *(const short8*)(Ab + (size_t)arow * 256 + k0 + lk);
        } else {
            if (arow < M) {
                const float* ap = Af + (size_t)arow * 256 + k0 + lk;
                float4 v0 = *(const float4*)(ap);
                float4 v1 = *(const float4*)(ap + 4);
                af[0] = (short)f2bf(v0.x); af[1] = (short)f2bf(v0.y);
                af[2] = (short)f2bf(v0.z); af[3] = (short)f2bf(v0.w);
                af[4] = (short)f2bf(v1.x); af[5] = (short)f2bf(v1.y);
                af[6] = (short)f2bf(v1.z); af[7] = (short)f2bf(v1.w);
            }
        }
#pragma unroll
        for (int nt = 0; nt < NT; ++nt) {
            short8 bf = *(const short8*)(Bl + (size_t)nt * 16 * 256 + k0);
            acc[nt] = __builtin_amdgcn_mfma_f32_16x16x32_bf16(af, bf, acc[nt], 0, 0, 0);
        }
    }

    // attention vectors for fused el/er
    float alv[HEL > 0 ? NT : 1], arv[HEL > 0 ? NT : 1];
    if (HEL > 0) {
#pragma unroll
        for (int nt = 0; nt < NT; ++nt) {
            alv[nt] = al[nt * 16 + lm];
            arv[nt] = ar[nt * 16 + lm];
        }
    }

#pragma unroll
    for (int j = 0; j < 4; ++j) {
        int row = m0 + w * 16 + (l >> 4) * 4 + j;
        if (row < M) {
#pragma unroll
            for (int nt = 0; nt < NT; ++nt) {
                int gcol = nt * 16 + lm;
                float v = acc[nt][j];
                if (bias) v += bias[gcol];
                if (OUTF32) Cf[(size_t)row * N + gcol] = v;
                else        Cb[(size_t)row * N + gcol] = f2bf(v);
            }
            if (HEL > 0) {
#pragma unroll
                for (int h = 0; h < HEL; ++h) {
                    float sl = 0.f, sr = 0.f;
#pragma unroll
                    for (int q = 0; q < NT / HEL; ++q) {
                        int nt = h * (NT / HEL) + q;
                        float v = acc[nt][j];
                        sl += v * alv[nt];
                        sr += v * arv[nt];
                    }
#pragma unroll
                    for (int mm = 1; mm < 16; mm <<= 1) {
                        sl += __shfl_xor(sl, mm, 64);
                        sr += __shfl_xor(sr, mm, 64);
                    }
                    if (lm == 0) {
                        el[(size_t)row * HEL + h] = sl;
                        er[(size_t)row * HEL + h] = sr;
                    }
                }
            }
        }
    }
}

// ---------------- aggregation: inline softmax weight + scalar (saddr) gather-FMA ----------
template<int H, bool ELU, bool RESID>
__global__ __launch_bounds__(256) void k_agg3(
        const unsigned short* __restrict__ ft,
        const float* __restrict__ el, const float* __restrict__ er,
        const int* __restrict__ offs, const int* __restrict__ deg,
        const int* __restrict__ esrc,
        const unsigned short* __restrict__ resid16,
        const float* __restrict__ bias,
        unsigned short* __restrict__ out_bf,
        float* __restrict__ out_f) {
    int w = threadIdx.x >> 6;
    int n = blockIdx.x * 4 + w;
    int l = threadIdx.x & 63;
    int c = 4 * l;
    int st = __builtin_amdgcn_readfirstlane(offs[n]);
    int dg = __builtin_amdgcn_readfirstlane(deg[n]);
    if (st < 0 || dg < 0 || st > NEDGES || dg > NEDGES - st) dg = 0;
    float a0 = 0.f, a1 = 0.f, a2 = 0.f, a3 = 0.f, wsum = 0.f;
    const unsigned short* ftc = ft + c;

    if (H == 1) {
        float ern = er[n];
        for (int i = 0; i < dg; i += 64) {
            int idx = i + l;
            int sv = 0; float wv = 0.f;
            if (idx < dg) {
                sv = esrc[st + idx];
                float xv = el[sv] + ern;
                xv = (xv > 0.f) ? xv : 0.2f * xv;
                xv = fminf(xv, 60.f);
                wv = __expf(xv);
            }
            wsum += wv;
            int jmax = dg - i; if (jmax > 64) jmax = 64;
            int j = 0;
            for (; j + 4 <= jmax; j += 4) {
                int s0 = __builtin_amdgcn_readlane(sv, j + 0);
                int s1 = __builtin_amdgcn_readlane(sv, j + 1);
                int s2 = __builtin_amdgcn_readlane(sv, j + 2);
                int s3 = __builtin_amdgcn_readlane(sv, j + 3);
                float w0 = __int_as_float(__builtin_amdgcn_readlane(__float_as_int(wv), j + 0));
                float w1 = __int_as_float(__builtin_amdgcn_readlane(__float_as_int(wv), j + 1));
                float w2 = __int_as_float(__builtin_amdgcn_readlane(__float_as_int(wv), j + 2));
                float w3 = __int_as_float(__builtin_amdgcn_readlane(__float_as_int(wv), j + 3));
                ushort4 f0 = *(const ushort4*)(ftc + (size_t)s0 * CH);
                ushort4 f1 = *(const ushort4*)(ftc + (size_t)s1 * CH);
                ushort4 f2 = *(const ushort4*)(ftc + (size_t)s2 * CH);
                ushort4 f3 = *(const ushort4*)(ftc + (size_t)s3 * CH);
                a0 += w0 * bf2f(f0.x) + w1 * bf2f(f1.x) + w2 * bf2f(f2.x) + w3 * bf2f(f3.x);
                a1 += w0 * bf2f(f0.y) + w1 * bf2f(f1.y) + w2 * bf2f(f2.y) + w3 * bf2f(f3.y);
                a2 += w0 * bf2f(f0.z) + w1 * bf2f(f1.z) + w2 * bf2f(f2.z) + w3 * bf2f(f3.z);
                a3 += w0 * bf2f(f0.w) + w1 * bf2f(f1.w) + w2 * bf2f(f2.w) + w3 * bf2f(f3.w);
            }
            for (; j < jmax; ++j) {
                int s0 = __builtin_amdgcn_readlane(sv, j);
                float w0 = __int_as_float(__builtin_amdgcn_readlane(__float_as_int(wv), j));
                ushort4 f0 = *(const ushort4*)(ftc + (size_t)s0 * CH);
                a0 += w0 * bf2f(f0.x); a1 += w0 * bf2f(f0.y);
                a2 += w0 * bf2f(f0.z); a3 += w0 * bf2f(f0.w);
            }
        }
#pragma unroll
        for (int m = 1; m < 64; m <<= 1) wsum += __shfl_xor(wsum, m, 64);
    } else {
        int head = l & 3, slot = l >> 2;       // phase-1 role of this lane
        int h = l >> 4;                        // phase-2 head (c / 64)
        float ern = er[n * 4 + head];
        for (int i = 0; i < dg; i += 16) {
            int idx = i + slot;
            int sv = 0; float wv = 0.f;
            if (idx < dg) {
                sv = esrc[st + idx];
                float xv = el[sv * 4 + head] + ern;
                xv = (xv > 0.f) ? xv : 0.2f * xv;
                xv = fminf(xv, 60.f);
                wv = __expf(xv);
            }
            wsum += wv;
            int jmax = dg - i; if (jmax > 16) jmax = 16;
            int j = 0;
            for (; j + 4 <= jmax; j += 4) {
                int s0 = __builtin_amdgcn_readlane(sv, 4 * (j + 0));
                int s1 = __builtin_amdgcn_readlane(sv, 4 * (j + 1));
                int s2 = __builtin_amdgcn_readlane(sv, 4 * (j + 2));
                int s3 = __builtin_amdgcn_readlane(sv, 4 * (j + 3));
                float w0 = __shfl(wv, 4 * (j + 0) + h, 64);
                float w1 = __shfl(wv, 4 * (j + 1) + h, 64);
                float w2 = __shfl(wv, 4 * (j + 2) + h, 64);
                float w3 = __shfl(wv, 4 * (j + 3) + h, 64);
                ushort4 f0 = *(const ushort4*)(ftc + (size_t)s0 * CH);
                ushort4 f1 = *(const ushort4*)(ftc + (size_t)s1 * CH);
                ushort4 f2 = *(const ushort4*)(ftc + (size_t)s2 * CH);
                ushort4 f3 = *(const ushort4*)(ftc + (size_t)s3 * CH);
                a0 += w0 * bf2f(f0.x) + w1 * bf2f(f1.x) + w2 * bf2f(f2.x) + w3 * bf2f(f3.x);
                a1 += w0 * bf2f(f0.y) + w1 * bf2f(f1.y) + w2 * bf2f(f2.y) + w3 * bf2f(f3.y);
                a2 += w0 * bf2f(f0.z) + w1 * bf2f(f1.z) + w2 * bf2f(f2.z) + w3 * bf2f(f3.z);
                a3 += w0 * bf2f(f0.w) + w1 * bf2f(f1.w) + w2 * bf2f(f2.w) + w3 * bf2f(f3.w);
            }
            for (; j < jmax; ++j) {
                int s0 = __builtin_amdgcn_readlane(sv, 4 * j);
                float w0 = __shfl(wv, 4 * j + h, 64);
                ushort4 f0 = *(const ushort4*)(ftc + (size_t)s0 * CH);
                a0 += w0 * bf2f(f0.x); a1 += w0 * bf2f(f0.y);
                a2 += w0 * bf2f(f0.z); a3 += w0 * bf2f(f0.w);
            }
        }
#pragma unroll
        for (int m = 4; m < 64; m <<= 1) wsum += __shfl_xor(wsum, m, 64);
        wsum = __shfl(wsum, h, 64);
    }
    float inv = (wsum > 1e-30f) ? 1.0f / wsum : 0.0f;
    a0 *= inv; a1 *= inv; a2 *= inv; a3 *= inv;
    if (RESID) {
        ushort4 r = *(const ushort4*)(resid16 + (size_t)n * CH + c);
        a0 += bf2f(r.x); a1 += bf2f(r.y); a2 += bf2f(r.z); a3 += bf2f(r.w);
    }
    {
        float4 b = *(const float4*)(bias + c);
        a0 += b.x; a1 += b.y; a2 += b.z; a3 += b.w;
    }
    if (ELU) {
        a0 = (a0 > 0.f) ? a0 : __expf(a0) - 1.f;
        a1 = (a1 > 0.f) ? a1 : __expf(a1) - 1.f;
        a2 = (a2 > 0.f) ? a2 : __expf(a2) - 1.f;
        a3 = (a3 > 0.f) ? a3 : __expf(a3) - 1.f;
    }
    if (out_bf) {
        ushort4 ov; ov.x = f2bf(a0); ov.y = f2bf(a1); ov.z = f2bf(a2); ov.w = f2bf(a3);
        *(ushort4*)(out_bf + (size_t)n * CH + c) = ov;
    }
    if (out_f) {
        *(float4*)(out_f + (size_t)n * CH + c) = make_float4(a0, a1, a2, a3);
    }
}

// ---------------- launch ----------------

extern "C" void kernel_launch(void* const* d_in, const int* in_sizes, int n_in,
                              void* d_out, int out_size, void* d_ws, size_t ws_size,
                              hipStream_t stream) {
    const float* x   = (const float*)d_in[0];
    const int*   src = (const int*)d_in[1];
    const int*   dst = (const int*)d_in[2];
    const float* W0  = (const float*)d_in[3];
    const float* al0 = (const float*)d_in[4];
    const float* ar0 = (const float*)d_in[5];
    const float* b0  = (const float*)d_in[6];
    const float* W1  = (const float*)d_in[7];
    const float* al1 = (const float*)d_in[8];
    const float* ar1 = (const float*)d_in[9];
    const float* b1  = (const float*)d_in[10];
    const float* Wl  = (const float*)d_in[11];
    const float* bl  = (const float*)d_in[12];

    float* out_logits = (float*)d_out;
    float* out_h      = out_logits + (size_t)NNODES * NCLS;

    // scratch in the logits region (12.8 MB; we use ~6.0 MB), overwritten last
    char* ob = (char*)d_out;
    size_t oo = 0;
    auto oalloc = [&](size_t b) { char* p = ob + oo; oo += (b + 255) & ~(size_t)255; return p; };
    int*   esrc = (int*)oalloc((size_t)NEDGES * 4);
    int*   deg  = (int*)oalloc((size_t)NNODES * 4);
    int*   offs = (int*)oalloc((size_t)NNODES * 4);
    int*   curs = (int*)oalloc((size_t)NNODES * 4);
    int*   scn  = (int*)oalloc((size_t)NNODES * 4);
    float* el0  = (float*)oalloc((size_t)NNODES * 4 * 4);
    float* er0  = (float*)oalloc((size_t)NNODES * 4 * 4);
    float* el1  = (float*)oalloc((size_t)NNODES * 4);
    float* er1  = (float*)oalloc((size_t)NNODES * 4);

    // ws: ft (25.6) + h0bf (25.6) + weights (~0.3) [+ h1bf (25.6) if room]
    char* ws = (char*)d_ws;
    size_t o = 0;
    auto alloc = [&](size_t b) { char* p = ws + o; o += (b + 255) & ~(size_t)255; return p; };
    unsigned short* ft   = (unsigned short*)alloc((size_t)NNODES * CH * 2);
    unsigned short* h0bf = (unsigned short*)alloc((size_t)NNODES * CH * 2);
    unsigned short* w0t  = (unsigned short*)alloc(256 * 256 * 2);
    unsigned short* w1t  = (unsigned short*)alloc(256 * 256 * 2);
    unsigned short* wlt  = (unsigned short*)alloc(64 * 256 * 2);
    int*            part = (int*)alloc(1024);
    int*            dmy  = (int*)alloc(256);
    unsigned short* h1bf = nullptr;
    if (o + (size_t)NNODES * CH * 2 <= ws_size) {
        h1bf = (unsigned short*)alloc((size_t)NNODES * CH * 2);
    }

    // ---- setup + CSR build ----
    k_setup<<<(147456 + NNODES + 255) / 256, 256, 0, stream>>>(W0, W1, Wl, w0t, w1t, wlt, deg);
    k_hist<<<(NEDGES + 255) / 256, 256, 0, stream>>>(dst, deg);
    int nb = (NNODES + 255) / 256;
    k_scan1<<<nb, 256, 0, stream>>>(deg, scn, part, NNODES);
    k_scan1<<<1, 256, 0, stream>>>(part, part, dmy, nb);
    k_scan3<<<nb, 256, 0, stream>>>(scn, deg, part, offs, curs, NNODES);
    k_scatter<<<(NEDGES + 255) / 256, 256, 0, stream>>>(dst, src, curs, esrc);

    int gm = (NNODES + 63) / 64;  // 782
    // ---- layer 0: GEMM (LDS-free, fused el/er) + agg ----
    k_gemmd<256, false, false, 4><<<gm, 256, 0, stream>>>(
        x, w0t, nullptr, nullptr, ft, NNODES, CH, al0, ar0, el0, er0);
    k_agg3<4, true, false><<<NNODES / 4, 256, 0, stream>>>(ft, el0, er0, offs, deg, esrc,
                                                           nullptr, b0, h0bf, nullptr);
    // ---- layer 1 ----
    k_gemmd<256, true, false, 1><<<gm, 256, 0, stream>>>(
        h0bf, w1t, nullptr, nullptr, ft, NNODES, CH, al1, ar1, el1, er1);
    k_agg3<1, false, true><<<NNODES / 4, 256, 0, stream>>>(ft, el1, er1, offs, deg, esrc,
                                                           h0bf, b1, h1bf, out_h);
    // ---- classifier ----
    if (h1bf) {
        k_gemmd<64, true, true, 0><<<gm, 256, 0, stream>>>(
            h1bf, wlt, bl, out_logits, nullptr, NNODES, NCLS,
            nullptr, nullptr, nullptr, nullptr);
    } else {
        k_gemmd<64, false, true, 0><<<gm, 256, 0, stream>>>(
            out_h, wlt, bl, out_logits, nullptr, NNODES, NCLS,
            nullptr, nullptr, nullptr, nullptr);
    }
}

// Round 5
// 393.901 us; speedup vs baseline: 1.2609x; 1.2609x over previous
//
#include <hip/hip_runtime.h>
#include <hip/hip_bf16.h>
#include <stdint.h>

#define NNODES 50000
#define NEDGES 800000
#define CH     256
#define NCLS   64

typedef __attribute__((ext_vector_type(8))) short  short8;
typedef __attribute__((ext_vector_type(4))) float  floatx4;

__device__ __forceinline__ float bf2f(unsigned short u) {
    union { unsigned int i; float f; } v; v.i = ((unsigned int)u) << 16; return v.f;
}
__device__ __forceinline__ unsigned short f2bf(float f) {
    union { float f; unsigned int i; } v; v.f = f;
    unsigned int x = v.i;
    return (unsigned short)((x + 0x7fffu + ((x >> 16) & 1u)) >> 16);  // RNE
}

// async 16B global -> LDS (DMA; tracked by vmcnt, drained by __syncthreads)
__device__ __forceinline__ void gl_lds16(const void* g, void* l) {
    __builtin_amdgcn_global_load_lds(
        (const __attribute__((address_space(1))) unsigned int*)g,
        (__attribute__((address_space(3))) unsigned int*)l, 16, 0, 0);
}

// ------- fused setup: zero deg + transpose-convert weights + x -> bf16 cast -------
__global__ void k_setup(const float* __restrict__ W0, const float* __restrict__ W1,
                        const float* __restrict__ Wl, const float* __restrict__ x,
                        unsigned short* __restrict__ w0t, unsigned short* __restrict__ w1t,
                        unsigned short* __restrict__ wlt, unsigned short* __restrict__ xbf,
                        int* __restrict__ deg) {
    int i = blockIdx.x * 256 + threadIdx.x;
    if (i < 65536) {
        int r = i >> 8, c = i & 255;
        w0t[c * 256 + r] = f2bf(W0[i]);
    } else if (i < 131072) {
        int j = i - 65536;
        int r = j >> 8, c = j & 255;
        w1t[c * 256 + r] = f2bf(W1[j]);
    } else if (i < 147456) {
        int j = i - 131072;
        int r = j >> 6, c = j & 63;       // Wl is [256,64]
        wlt[c * 256 + r] = f2bf(Wl[j]);
    } else if (i < 147456 + NNODES) {
        deg[i - 147456] = 0;
    } else {
        int j = i - (147456 + NNODES);    // 8-elem chunk of x
        if (j < NNODES * CH / 8) {
            const float4* xp = (const float4*)(x + (size_t)j * 8);
            float4 v0 = xp[0], v1 = xp[1];
            ushort4 o0, o1;
            o0.x = f2bf(v0.x); o0.y = f2bf(v0.y); o0.z = f2bf(v0.z); o0.w = f2bf(v0.w);
            o1.x = f2bf(v1.x); o1.y = f2bf(v1.y); o1.z = f2bf(v1.z); o1.w = f2bf(v1.w);
            *(ushort4*)(xbf + (size_t)j * 8)     = o0;
            *(ushort4*)(xbf + (size_t)j * 8 + 4) = o1;
        }
    }
}

__global__ void k_hist(const int* __restrict__ dst, int* __restrict__ deg) {
    int e = blockIdx.x * 256 + threadIdx.x;
    if (e < NEDGES) {
        int d = dst[e];
        if ((unsigned)d < NNODES) atomicAdd(&deg[d], 1);
    }
}

__global__ void k_scan1(const int* __restrict__ in, int* __restrict__ out,
                        int* __restrict__ part, int n) {
    __shared__ int sm[256];
    int i = blockIdx.x * 256 + threadIdx.x;
    int v = (i < n) ? in[i] : 0;
    sm[threadIdx.x] = v;
    __syncthreads();
    for (int off = 1; off < 256; off <<= 1) {
        int t = (threadIdx.x >= (unsigned)off) ? sm[threadIdx.x - off] : 0;
        __syncthreads();
        sm[threadIdx.x] += t;
        __syncthreads();
    }
    if (i < n) out[i] = sm[threadIdx.x];
    if (threadIdx.x == 255) part[blockIdx.x] = sm[255];
}

__global__ void k_scan3(const int* __restrict__ scn, const int* __restrict__ deg,
                        const int* __restrict__ part, int* __restrict__ offs,
                        int* __restrict__ cursor, int n) {
    int i = blockIdx.x * 256 + threadIdx.x;
    if (i < n) {
        int add = (blockIdx.x > 0) ? part[blockIdx.x - 1] : 0;
        int o = scn[i] - deg[i] + add;
        offs[i] = o; cursor[i] = o;
    }
}

__global__ void k_scatter(const int* __restrict__ dst, const int* __restrict__ src,
                          int* __restrict__ cursor, int* __restrict__ esrc) {
    int e = blockIdx.x * 256 + threadIdx.x;
    if (e < NEDGES) {
        int d = dst[e];
        if ((unsigned)d < NNODES) {
            int p = atomicAdd(&cursor[d], 1);
            if ((unsigned)p < NEDGES) esrc[p] = src[e];
        }
    }
}

// ---------------- GEMM: 64(M) x BN(N) per block, B staged via global_load_lds ------------
// A fragments: direct global->reg (each row used by exactly one wave; no LDS round-trip).
// B: [2][BN][32] linear LDS double-buffer, 16B DMA staging, one __syncthreads per K-step
// (its vmcnt(0) drain completes the DMA). AF32: A is f32, convert in-reg (classifier
// fallback path only). HEL>0 fuses el/er epilogue (needs BN==N==CH).
template<int BN, bool AF32, bool OUTF32, int HEL>
__global__ __launch_bounds__(256) void k_gemml(const void* __restrict__ Av,
                                               const unsigned short* __restrict__ BT,
                                               const float* __restrict__ bias,
                                               float* __restrict__ Cf,
                                               unsigned short* __restrict__ Cb,
                                               int M, int N,
                                               const float* __restrict__ al,
                                               const float* __restrict__ ar,
                                               float* __restrict__ el,
                                               float* __restrict__ er) {
    constexpr int NT  = BN / 16;
    constexpr int RPW = BN / 4;      // B rows staged per wave per K-step
    constexpr int P   = RPW / 16;    // gl_lds16 instructions per wave per K-step
    __shared__ unsigned short Bs[2][BN][32];
    const int t  = threadIdx.x;
    const int w  = t >> 6, l = t & 63;
    const int lm = l & 15, lg = l >> 4;        // fragment row / k-group
    const int m0 = blockIdx.x * 64;
    const int arow = m0 + w * 16 + lm;
    const unsigned short* Ab = (const unsigned short*)Av;
    const float*          Af = (const float*)Av;

    // staging source position of this lane (row advances by p*16)
    const int srow  = w * RPW + (l >> 2);
    const int sslot = (l & 3) * 8;             // elems (16 B)

    floatx4 acc[NT];
#pragma unroll
    for (int nt = 0; nt < NT; ++nt) acc[nt] = (floatx4)0.0f;

    // ---- prologue: stage B k-slice 0; load A fragment 0 ----
#pragma unroll
    for (int p = 0; p < P; ++p)
        gl_lds16(BT + (size_t)(srow + p * 16) * 256 + sslot,
                 &Bs[0][w * RPW + p * 16][0]);
    short8 af0 = (short8)0, af1 = (short8)0;
    if (arow < M) {
        if (AF32) {
            const float* ap = Af + (size_t)arow * 256 + lg * 8;
            float4 v0 = *(const float4*)(ap), v1 = *(const float4*)(ap + 4);
            af0[0] = (short)f2bf(v0.x); af0[1] = (short)f2bf(v0.y);
            af0[2] = (short)f2bf(v0.z); af0[3] = (short)f2bf(v0.w);
            af0[4] = (short)f2bf(v1.x); af0[5] = (short)f2bf(v1.y);
            af0[6] = (short)f2bf(v1.z); af0[7] = (short)f2bf(v1.w);
        } else {
            af0 = *(const short8*)(Ab + (size_t)arow * 256 + lg * 8);
        }
    }
    __syncthreads();

    int cur = 0;
    for (int ks = 0; ks < 8; ++ks) {
        if (ks < 7) {
            int k1 = (ks + 1) * 32;
#pragma unroll
            for (int p = 0; p < P; ++p)
                gl_lds16(BT + (size_t)(srow + p * 16) * 256 + k1 + sslot,
                         &Bs[cur ^ 1][w * RPW + p * 16][0]);
            af1 = (short8)0;
            if (arow < M) {
                if (AF32) {
                    const float* ap = Af + (size_t)arow * 256 + k1 + lg * 8;
                    float4 v0 = *(const float4*)(ap), v1 = *(const float4*)(ap + 4);
                    af1[0] = (short)f2bf(v0.x); af1[1] = (short)f2bf(v0.y);
                    af1[2] = (short)f2bf(v0.z); af1[3] = (short)f2bf(v0.w);
                    af1[4] = (short)f2bf(v1.x); af1[5] = (short)f2bf(v1.y);
                    af1[6] = (short)f2bf(v1.z); af1[7] = (short)f2bf(v1.w);
                } else {
                    af1 = *(const short8*)(Ab + (size_t)arow * 256 + k1 + lg * 8);
                }
            }
        }
#pragma unroll
        for (int nt = 0; nt < NT; ++nt) {
            short8 bf = *(const short8*)&Bs[cur][nt * 16 + lm][lg * 8];
            acc[nt] = __builtin_amdgcn_mfma_f32_16x16x32_bf16(af0, bf, acc[nt], 0, 0, 0);
        }
        af0 = af1;
        if (ks < 7) { __syncthreads(); cur ^= 1; }
    }

    // attention vectors for fused el/er
    float alv[HEL > 0 ? NT : 1], arv[HEL > 0 ? NT : 1];
    if (HEL > 0) {
#pragma unroll
        for (int nt = 0; nt < NT; ++nt) {
            alv[nt] = al[nt * 16 + lm];
            arv[nt] = ar[nt * 16 + lm];
        }
    }

#pragma unroll
    for (int j = 0; j < 4; ++j) {
        int row = m0 + w * 16 + (l >> 4) * 4 + j;
        if (row < M) {
#pragma unroll
            for (int nt = 0; nt < NT; ++nt) {
                int gcol = nt * 16 + lm;
                float v = acc[nt][j];
                if (bias) v += bias[gcol];
                if (OUTF32) Cf[(size_t)row * N + gcol] = v;
                else        Cb[(size_t)row * N + gcol] = f2bf(v);
            }
            if (HEL > 0) {
#pragma unroll
                for (int h = 0; h < HEL; ++h) {
                    float sl = 0.f, sr = 0.f;
#pragma unroll
                    for (int q = 0; q < NT / HEL; ++q) {
                        int nt = h * (NT / HEL) + q;
                        float v = acc[nt][j];
                        sl += v * alv[nt];
                        sr += v * arv[nt];
                    }
#pragma unroll
                    for (int mm = 1; mm < 16; mm <<= 1) {
                        sl += __shfl_xor(sl, mm, 64);
                        sr += __shfl_xor(sr, mm, 64);
                    }
                    if (lm == 0) {
                        el[(size_t)row * HEL + h] = sl;
                        er[(size_t)row * HEL + h] = sr;
                    }
                }
            }
        }
    }
}

// ---------------- aggregation: inline softmax weight + scalar (saddr) gather-FMA ----------
template<int H, bool ELU, bool RESID>
__global__ __launch_bounds__(256) void k_agg3(
        const unsigned short* __restrict__ ft,
        const float* __restrict__ el, const float* __restrict__ er,
        const int* __restrict__ offs, const int* __restrict__ deg,
        const int* __restrict__ esrc,
        const unsigned short* __restrict__ resid16,
        const float* __restrict__ bias,
        unsigned short* __restrict__ out_bf,
        float* __restrict__ out_f) {
    int w = threadIdx.x >> 6;
    int n = blockIdx.x * 4 + w;
    int l = threadIdx.x & 63;
    int c = 4 * l;
    int st = __builtin_amdgcn_readfirstlane(offs[n]);
    int dg = __builtin_amdgcn_readfirstlane(deg[n]);
    if (st < 0 || dg < 0 || st > NEDGES || dg > NEDGES - st) dg = 0;
    float a0 = 0.f, a1 = 0.f, a2 = 0.f, a3 = 0.f, wsum = 0.f;
    const unsigned short* ftc = ft + c;

    if (H == 1) {
        float ern = er[n];
        for (int i = 0; i < dg; i += 64) {
            int idx = i + l;
            int sv = 0; float wv = 0.f;
            if (idx < dg) {
                sv = esrc[st + idx];
                float xv = el[sv] + ern;
                xv = (xv > 0.f) ? xv : 0.2f * xv;
                xv = fminf(xv, 60.f);
                wv = __expf(xv);
            }
            wsum += wv;
            int jmax = dg - i; if (jmax > 64) jmax = 64;
            int j = 0;
            for (; j + 4 <= jmax; j += 4) {
                int s0 = __builtin_amdgcn_readlane(sv, j + 0);
                int s1 = __builtin_amdgcn_readlane(sv, j + 1);
                int s2 = __builtin_amdgcn_readlane(sv, j + 2);
                int s3 = __builtin_amdgcn_readlane(sv, j + 3);
                float w0 = __int_as_float(__builtin_amdgcn_readlane(__float_as_int(wv), j + 0));
                float w1 = __int_as_float(__builtin_amdgcn_readlane(__float_as_int(wv), j + 1));
                float w2 = __int_as_float(__builtin_amdgcn_readlane(__float_as_int(wv), j + 2));
                float w3 = __int_as_float(__builtin_amdgcn_readlane(__float_as_int(wv), j + 3));
                ushort4 f0 = *(const ushort4*)(ftc + (size_t)s0 * CH);
                ushort4 f1 = *(const ushort4*)(ftc + (size_t)s1 * CH);
                ushort4 f2 = *(const ushort4*)(ftc + (size_t)s2 * CH);
                ushort4 f3 = *(const ushort4*)(ftc + (size_t)s3 * CH);
                a0 += w0 * bf2f(f0.x) + w1 * bf2f(f1.x) + w2 * bf2f(f2.x) + w3 * bf2f(f3.x);
                a1 += w0 * bf2f(f0.y) + w1 * bf2f(f1.y) + w2 * bf2f(f2.y) + w3 * bf2f(f3.y);
                a2 += w0 * bf2f(f0.z) + w1 * bf2f(f1.z) + w2 * bf2f(f2.z) + w3 * bf2f(f3.z);
                a3 += w0 * bf2f(f0.w) + w1 * bf2f(f1.w) + w2 * bf2f(f2.w) + w3 * bf2f(f3.w);
            }
            for (; j < jmax; ++j) {
                int s0 = __builtin_amdgcn_readlane(sv, j);
                float w0 = __int_as_float(__builtin_amdgcn_readlane(__float_as_int(wv), j));
                ushort4 f0 = *(const ushort4*)(ftc + (size_t)s0 * CH);
                a0 += w0 * bf2f(f0.x); a1 += w0 * bf2f(f0.y);
                a2 += w0 * bf2f(f0.z); a3 += w0 * bf2f(f0.w);
            }
        }
#pragma unroll
        for (int m = 1; m < 64; m <<= 1) wsum += __shfl_xor(wsum, m, 64);
    } else {
        int head = l & 3, slot = l >> 2;       // phase-1 role of this lane
        int h = l >> 4;                        // phase-2 head (c / 64)
        float ern = er[n * 4 + head];
        for (int i = 0; i < dg; i += 16) {
            int idx = i + slot;
            int sv = 0; float wv = 0.f;
            if (idx < dg) {
                sv = esrc[st + idx];
                float xv = el[sv * 4 + head] + ern;
                xv = (xv > 0.f) ? xv : 0.2f * xv;
                xv = fminf(xv, 60.f);
                wv = __expf(xv);
            }
            wsum += wv;
            int jmax = dg - i; if (jmax > 16) jmax = 16;
            int j = 0;
            for (; j + 4 <= jmax; j += 4) {
                int s0 = __builtin_amdgcn_readlane(sv, 4 * (j + 0));
                int s1 = __builtin_amdgcn_readlane(sv, 4 * (j + 1));
                int s2 = __builtin_amdgcn_readlane(sv, 4 * (j + 2));
                int s3 = __builtin_amdgcn_readlane(sv, 4 * (j + 3));
                float w0 = __shfl(wv, 4 * (j + 0) + h, 64);
                float w1 = __shfl(wv, 4 * (j + 1) + h, 64);
                float w2 = __shfl(wv, 4 * (j + 2) + h, 64);
                float w3 = __shfl(wv, 4 * (j + 3) + h, 64);
                ushort4 f0 = *(const ushort4*)(ftc + (size_t)s0 * CH);
                ushort4 f1 = *(const ushort4*)(ftc + (size_t)s1 * CH);
                ushort4 f2 = *(const ushort4*)(ftc + (size_t)s2 * CH);
                ushort4 f3 = *(const ushort4*)(ftc + (size_t)s3 * CH);
                a0 += w0 * bf2f(f0.x) + w1 * bf2f(f1.x) + w2 * bf2f(f2.x) + w3 * bf2f(f3.x);
                a1 += w0 * bf2f(f0.y) + w1 * bf2f(f1.y) + w2 * bf2f(f2.y) + w3 * bf2f(f3.y);
                a2 += w0 * bf2f(f0.z) + w1 * bf2f(f1.z) + w2 * bf2f(f2.z) + w3 * bf2f(f3.z);
                a3 += w0 * bf2f(f0.w) + w1 * bf2f(f1.w) + w2 * bf2f(f2.w) + w3 * bf2f(f3.w);
            }
            for (; j < jmax; ++j) {
                int s0 = __builtin_amdgcn_readlane(sv, 4 * j);
                float w0 = __shfl(wv, 4 * j + h, 64);
                ushort4 f0 = *(const ushort4*)(ftc + (size_t)s0 * CH);
                a0 += w0 * bf2f(f0.x); a1 += w0 * bf2f(f0.y);
                a2 += w0 * bf2f(f0.z); a3 += w0 * bf2f(f0.w);
            }
        }
#pragma unroll
        for (int m = 4; m < 64; m <<= 1) wsum += __shfl_xor(wsum, m, 64);
        wsum = __shfl(wsum, h, 64);
    }
    float inv = (wsum > 1e-30f) ? 1.0f / wsum : 0.0f;
    a0 *= inv; a1 *= inv; a2 *= inv; a3 *= inv;
    if (RESID) {
        ushort4 r = *(const ushort4*)(resid16 + (size_t)n * CH + c);
        a0 += bf2f(r.x); a1 += bf2f(r.y); a2 += bf2f(r.z); a3 += bf2f(r.w);
    }
    {
        float4 b = *(const float4*)(bias + c);
        a0 += b.x; a1 += b.y; a2 += b.z; a3 += b.w;
    }
    if (ELU) {
        a0 = (a0 > 0.f) ? a0 : __expf(a0) - 1.f;
        a1 = (a1 > 0.f) ? a1 : __expf(a1) - 1.f;
        a2 = (a2 > 0.f) ? a2 : __expf(a2) - 1.f;
        a3 = (a3 > 0.f) ? a3 : __expf(a3) - 1.f;
    }
    if (out_bf) {
        ushort4 ov; ov.x = f2bf(a0); ov.y = f2bf(a1); ov.z = f2bf(a2); ov.w = f2bf(a3);
        *(ushort4*)(out_bf + (size_t)n * CH + c) = ov;
    }
    if (out_f) {
        *(float4*)(out_f + (size_t)n * CH + c) = make_float4(a0, a1, a2, a3);
    }
}

// ---------------- launch ----------------

extern "C" void kernel_launch(void* const* d_in, const int* in_sizes, int n_in,
                              void* d_out, int out_size, void* d_ws, size_t ws_size,
                              hipStream_t stream) {
    const float* x   = (const float*)d_in[0];
    const int*   src = (const int*)d_in[1];
    const int*   dst = (const int*)d_in[2];
    const float* W0  = (const float*)d_in[3];
    const float* al0 = (const float*)d_in[4];
    const float* ar0 = (const float*)d_in[5];
    const float* b0  = (const float*)d_in[6];
    const float* W1  = (const float*)d_in[7];
    const float* al1 = (const float*)d_in[8];
    const float* ar1 = (const float*)d_in[9];
    const float* b1  = (const float*)d_in[10];
    const float* Wl  = (const float*)d_in[11];
    const float* bl  = (const float*)d_in[12];

    float* out_logits = (float*)d_out;
    float* out_h      = out_logits + (size_t)NNODES * NCLS;

    // scratch in the logits region (12.8 MB; we use ~6.0 MB), overwritten last
    char* ob = (char*)d_out;
    size_t oo = 0;
    auto oalloc = [&](size_t b) { char* p = ob + oo; oo += (b + 255) & ~(size_t)255; return p; };
    int*   esrc = (int*)oalloc((size_t)NEDGES * 4);
    int*   deg  = (int*)oalloc((size_t)NNODES * 4);
    int*   offs = (int*)oalloc((size_t)NNODES * 4);
    int*   curs = (int*)oalloc((size_t)NNODES * 4);
    int*   scn  = (int*)oalloc((size_t)NNODES * 4);
    float* el0  = (float*)oalloc((size_t)NNODES * 4 * 4);
    float* er0  = (float*)oalloc((size_t)NNODES * 4 * 4);
    float* el1  = (float*)oalloc((size_t)NNODES * 4);
    float* er1  = (float*)oalloc((size_t)NNODES * 4);

    // xbf (25.6 MB) lives in the out_h region: dead after GEMM-0, long before agg<1> writes out_h
    unsigned short* xbf = (unsigned short*)out_h;

    // ws: ft (25.6) + h0bf (25.6) + weights (~0.3) [+ h1bf (25.6) if room]
    char* ws = (char*)d_ws;
    size_t o = 0;
    auto alloc = [&](size_t b) { char* p = ws + o; o += (b + 255) & ~(size_t)255; return p; };
    unsigned short* ft   = (unsigned short*)alloc((size_t)NNODES * CH * 2);
    unsigned short* h0bf = (unsigned short*)alloc((size_t)NNODES * CH * 2);
    unsigned short* w0t  = (unsigned short*)alloc(256 * 256 * 2);
    unsigned short* w1t  = (unsigned short*)alloc(256 * 256 * 2);
    unsigned short* wlt  = (unsigned short*)alloc(64 * 256 * 2);
    int*            part = (int*)alloc(1024);
    int*            dmy  = (int*)alloc(256);
    unsigned short* h1bf = nullptr;
    if (o + (size_t)NNODES * CH * 2 <= ws_size) {
        h1bf = (unsigned short*)alloc((size_t)NNODES * CH * 2);
    }

    // ---- setup (weights + xcast) + CSR build ----
    int setup_items = 147456 + NNODES + NNODES * CH / 8;
    k_setup<<<(setup_items + 255) / 256, 256, 0, stream>>>(W0, W1, Wl, x,
                                                           w0t, w1t, wlt, xbf, deg);
    k_hist<<<(NEDGES + 255) / 256, 256, 0, stream>>>(dst, deg);
    int nb = (NNODES + 255) / 256;
    k_scan1<<<nb, 256, 0, stream>>>(deg, scn, part, NNODES);
    k_scan1<<<1, 256, 0, stream>>>(part, part, dmy, nb);
    k_scan3<<<nb, 256, 0, stream>>>(scn, deg, part, offs, curs, NNODES);
    k_scatter<<<(NEDGES + 255) / 256, 256, 0, stream>>>(dst, src, curs, esrc);

    int gm = (NNODES + 63) / 64;  // 782
    // ---- layer 0: GEMM (gl_lds B-staging, A direct, fused el/er) + agg ----
    k_gemml<256, false, false, 4><<<gm, 256, 0, stream>>>(
        xbf, w0t, nullptr, nullptr, ft, NNODES, CH, al0, ar0, el0, er0);
    k_agg3<4, true, false><<<NNODES / 4, 256, 0, stream>>>(ft, el0, er0, offs, deg, esrc,
                                                           nullptr, b0, h0bf, nullptr);
    // ---- layer 1 ----
    k_gemml<256, false, false, 1><<<gm, 256, 0, stream>>>(
        h0bf, w1t, nullptr, nullptr, ft, NNODES, CH, al1, ar1, el1, er1);
    k_agg3<1, false, true><<<NNODES / 4, 256, 0, stream>>>(ft, el1, er1, offs, deg, esrc,
                                                           h0bf, b1, h1bf, out_h);
    // ---- classifier ----
    if (h1bf) {
        k_gemml<64, false, true, 0><<<gm, 256, 0, stream>>>(
            h1bf, wlt, bl, out_logits, nullptr, NNODES, NCLS,
            nullptr, nullptr, nullptr, nullptr);
    } else {
        k_gemml<64, true, true, 0><<<gm, 256, 0, stream>>>(
            out_h, wlt, bl, out_logits, nullptr, NNODES, NCLS,
            nullptr, nullptr, nullptr, nullptr);
    }
}